// Round 1
// 155.579 us; speedup vs baseline: 1.0465x; 1.0465x over previous
//
#include <hip/hip_runtime.h>
#include <stdint.h>

typedef __attribute__((ext_vector_type(8))) short short8;
typedef __attribute__((ext_vector_type(4))) float floatx4;
typedef __attribute__((ext_vector_type(16))) float floatx16;
typedef __attribute__((ext_vector_type(4))) unsigned int uintx4;

#define BB 2
#define NN 2048
#define DD 768
#define HH 12
#define HDD 64
#define MM (BB*NN)   // 4096

__device__ __forceinline__ unsigned short f2bf(float f) {
  unsigned int u = __builtin_bit_cast(unsigned int, f);
  u += 0x7fffu + ((u >> 16) & 1u);          // RNE; inputs are finite
  return (unsigned short)(u >> 16);
}
__device__ __forceinline__ float bf2f(unsigned short u) {
  unsigned int v = ((unsigned int)u) << 16;
  return __builtin_bit_cast(float, v);
}

// async global->LDS DMA, 16B per lane; LDS dest = wave-uniform base + lane*16
__device__ __forceinline__ void gld16(const unsigned short* g, unsigned short* l) {
  __builtin_amdgcn_global_load_lds(
      (const __attribute__((address_space(1))) void*)g,
      (__attribute__((address_space(3))) void*)l, 16, 0, 0);
}

// pack 2 fp32 -> 1 dword of 2 bf16 (RNE), single VALU op
__device__ __forceinline__ unsigned int cvtpk_bf16(float a, float b) {
  unsigned int r;
  asm("v_cvt_pk_bf16_f32 %0, %1, %2" : "=v"(r) : "v"(a), "v"(b));
  return r;
}
// swap upper 32 lanes of a with lower 32 lanes of b (both modified)
__device__ __forceinline__ void plswap(unsigned int& a, unsigned int& b) {
  asm("v_permlane32_swap_b32 %0, %1" : "+v"(a), "+v"(b));
}

// ---------------- fused fp32 -> bf16 convert (all three inputs) ----------------
__global__ void cvt_all(const float* __restrict__ x, const float* __restrict__ wq,
                        const float* __restrict__ wp, unsigned short* __restrict__ xb,
                        unsigned short* __restrict__ wqb, unsigned short* __restrict__ wpb) {
  const int n1 = MM*DD/4, n2 = 3*DD*DD/4, n3 = DD*DD/4;
  int i = blockIdx.x * blockDim.x + threadIdx.x;
  const float* s; unsigned short* d; int j;
  if (i < n1)            { s = x;  d = xb;  j = i; }
  else if (i < n1+n2)    { s = wq; d = wqb; j = i - n1; }
  else if (i < n1+n2+n3) { s = wp; d = wpb; j = i - n1 - n2; }
  else return;
  float4 v = reinterpret_cast<const float4*>(s)[j];
  unsigned int lo = (unsigned int)f2bf(v.x) | ((unsigned int)f2bf(v.y) << 16);
  unsigned int hi = (unsigned int)f2bf(v.z) | ((unsigned int)f2bf(v.w) << 16);
  reinterpret_cast<uint2*>(d)[j] = make_uint2(lo, hi);
}

// ---------------- bf16 MFMA GEMM: C[m,n] = sum_k A[m,k]*Bt[n,k] ----------------
// Tile MT x NT, depth BK, gld16 staging with XOR-chunk swizzle (source-side, so
// the LDS dest stays lane-linear as gld16 requires): LDS slot `part` of row r
// holds global chunk part^(r&(PARTS-1)); frag reads un-swizzle -> b128 reads hit
// all 32 banks (2-way max, free per m136). Bit-identical math to r13 (same K order).
// MODE 0: bf16 store. MODE 1: fp32+bias. MODE 2: fused RoPE+relayout epilogue.
template<int MODE, int MT, int NT, int BK>
__global__ __launch_bounds__(256) void gemm_bt(
    const unsigned short* __restrict__ A,   // M x K bf16 row-major
    const unsigned short* __restrict__ Bt,  // Nn x K bf16 row-major
    void* __restrict__ Cout, const float* __restrict__ bias,
    int Nn, int K,
    const float* __restrict__ pos,
    unsigned short* __restrict__ qb2, unsigned short* __restrict__ kb2,
    unsigned short* __restrict__ vb2)
{
  constexpr int MTC = MT / 32;              // 16-row subtiles per wave (m-dim)
  constexpr int NTC = NT / 32;              // 16-col subtiles per wave (n-dim)
  constexpr int PARTS = BK / 8;             // 16B chunks per row
  __shared__ __align__(16) unsigned short as_[MT*BK];
  __shared__ __align__(16) unsigned short bs_[NT*BK];
  const int t = threadIdx.x;
  const int w = t >> 6, lane = t & 63;
  const int quad = lane >> 4, l16 = lane & 15;
  const int wm = (w >> 1) * (MT/2), wn = (w & 1) * (NT/2);
  const int m0 = blockIdx.y * MT, n0 = blockIdx.x * NT;

  const floatx4 fz = {0.f, 0.f, 0.f, 0.f};
  floatx4 acc[MTC][NTC];
#pragma unroll
  for (int mt = 0; mt < MTC; mt++)
#pragma unroll
    for (int nt = 0; nt < NTC; nt++) acc[mt][nt] = fz;

  for (int k0 = 0; k0 < K; k0 += BK) {
    __syncthreads();
#pragma unroll
    for (int i = 0; i < MT*PARTS/256; i++) {  // A staging
      int c = t + i * 256;
      int row = c / PARTS, part = c % PARTS;
      int sp = part ^ (row & (PARTS-1));
      gld16(&A[(size_t)(m0 + row)*K + k0 + sp*8], &as_[c*8]);
    }
#pragma unroll
    for (int i = 0; i < NT*PARTS/256; i++) {  // B staging
      int c = t + i * 256;
      int row = c / PARTS, part = c % PARTS;
      int sp = part ^ (row & (PARTS-1));
      gld16(&Bt[(size_t)(n0 + row)*K + k0 + sp*8], &bs_[c*8]);
    }
    __syncthreads();                        // drains vmcnt
#pragma unroll
    for (int kh = 0; kh < BK/32; kh++) {
      short8 af[MTC], bfr[NTC];
#pragma unroll
      for (int mt = 0; mt < MTC; mt++) {
        int row = wm + mt*16 + l16;
        int slot = (kh*4 + quad) ^ (row & (PARTS-1));
        af[mt] = *reinterpret_cast<const short8*>(&as_[row*BK + slot*8]);
      }
#pragma unroll
      for (int nt = 0; nt < NTC; nt++) {
        int row = wn + nt*16 + l16;
        int slot = (kh*4 + quad) ^ (row & (PARTS-1));
        bfr[nt] = *reinterpret_cast<const short8*>(&bs_[row*BK + slot*8]);
      }
#pragma unroll
      for (int mt = 0; mt < MTC; mt++)
#pragma unroll
        for (int nt = 0; nt < NTC; nt++)
          acc[mt][nt] = __builtin_amdgcn_mfma_f32_16x16x32_bf16(af[mt], bfr[nt], acc[mt][nt], 0, 0, 0);
    }
  }
  // epilogue: C/D layout col=lane&15, row=quad*4+reg (m89-verified)
  if (MODE == 2) {
    const int region = n0 / DD;             // 0=Q, 1=K, 2=V
    const int nl0 = n0 - region * DD;
    const int head = (nl0 + wn) / HDD;      // wave-half owns one head (64 cols)
    if (region < 2) {
      // Q/K: rotate pairs (hd, hd+32) = (acc[mt][nt], acc[mt][nt+2]), nt in {0,1}
#pragma unroll
      for (int mt = 0; mt < MTC; mt++)
#pragma unroll
        for (int r = 0; r < 4; r++) {
          int gm = m0 + wm + mt*16 + quad*4 + r;
          int bq = gm >> 11, nseq = gm & (NN-1);
          size_t base = ((size_t)(bq*HH + head)*NN + nseq) * HDD;
#pragma unroll
          for (int nt = 0; nt < 2; nt++) {
            int hd = nt*16 + l16;
            float t1 = pos[nseq*HDD + hd], t2 = pos[nseq*HDD + hd + 32];
            float s1, c1, s2, c2;
            __sincosf(t1, &s1, &c1);
            __sincosf(t2, &s2, &c2);
            float a1 = acc[mt][nt][r], a2 = acc[mt][nt+2][r];
            if (region == 0) {              // Q: scale folded, plain layout
              qb2[base + hd]      = f2bf((a1*c1 - a2*s1) * 0.125f);
              qb2[base + hd + 32] = f2bf((a2*c2 + a1*s2) * 0.125f);
            } else {                        // K: chunk-XOR swizzle (hd>>3)^(n&7)
              int sl1 = (hd >> 3) ^ (nseq & 7);
              int sl2 = ((hd >> 3) + 4) ^ (nseq & 7);
              kb2[base + sl1*8 + (hd & 7)] = f2bf(a1*c1 - a2*s1);
              kb2[base + sl2*8 + (hd & 7)] = f2bf(a2*c2 + a1*s2);
            }
          }
        }
    } else {
      // V^T: reg quad r=0..3 are 4 consecutive seq -> one b64 pack per (mt,nt)
#pragma unroll
      for (int mt = 0; mt < MTC; mt++)
#pragma unroll
        for (int nt = 0; nt < NTC; nt++) {
          int hd = nt*16 + l16;
          int seqb = m0 + wm + mt*16 + quad*4;
          int bq = seqb >> 11, nsb = seqb & (NN-1);
          unsigned int p0 = (unsigned int)f2bf(acc[mt][nt][0]) | ((unsigned int)f2bf(acc[mt][nt][1]) << 16);
          unsigned int p1 = (unsigned int)f2bf(acc[mt][nt][2]) | ((unsigned int)f2bf(acc[mt][nt][3]) << 16);
          int slot = ((nsb >> 3) & 15) ^ (hd & 7);
          size_t addr = ((size_t)(bq*HH + head)*HDD + hd) * NN + (nsb & ~127) + slot*8 + (nsb & 7);
          *(uint2*)&vb2[addr] = make_uint2(p0, p1);
        }
    }
  } else {
#pragma unroll
    for (int mt = 0; mt < MTC; mt++)
#pragma unroll
      for (int nt = 0; nt < NTC; nt++)
#pragma unroll
        for (int r = 0; r < 4; r++) {
          int gm = m0 + wm + mt*16 + quad*4 + r;
          int gn = n0 + wn + nt*16 + l16;
          float v = acc[mt][nt][r];
          if (MODE == 0)
            reinterpret_cast<unsigned short*>(Cout)[(size_t)gm * Nn + gn] = f2bf(v);
          else
            reinterpret_cast<float*>(Cout)[(size_t)gm * Nn + gn] = v + bias[gn];
        }
  }
}

// ---------------- flash attention ----------------
// v2: P never touches LDS. S^T = mfma(K,Q) leaves lane l32 holding the full
// P-column for q=l32 (keys at (r&3)+8*(r>>2)+4*hf, m214-verified layout).
// cvt_pk_bf16 pairs + permlane32_swap exchange the hf halves in-register,
// producing the PV A-fragments directly (T12). ps buffer removed; the fp32
// O-merge reuses ks (dead after the loop) -> LDS 48.5KB -> 33.3KB (4 blk/CU).
__global__ __launch_bounds__(256, 4) void flash_attn(
    const unsigned short* __restrict__ qb, const unsigned short* __restrict__ kb,
    const unsigned short* __restrict__ vb, unsigned short* __restrict__ ob)
{
  __shared__ __align__(16) unsigned short ks[128*64];   // [key][d], chunk-swizzled; reused as fp32 O-merge
  __shared__ __align__(16) unsigned short vt[64*128];   // [hd][key], chunk-swizzled
  __shared__ __align__(16) float lsd[128];              // per-wave partial l
  const int qt = blockIdx.x, bh = blockIdx.y;
  const int b = bh / HH, hh = bh % HH;
  const int t = threadIdx.x;
  const int w = t >> 6, lane = t & 63;
  const int l32 = lane & 31, hf = lane >> 5;
  const int gq = w >> 1;                    // q-group: rows gq*32..gq*32+31
  const int kh = w & 1;                     // key-half within each 128-key tile
  const int q0 = qt * 64;
  const size_t kbase = (size_t)bh * (NN*HDD);

  // Q B-frags: lane holds Q[q=q0+gq*32+l32][d=s*16+hf*8+j]
  short8 qf[4];
  {
    const unsigned short* qp = &qb[((size_t)bh*NN + q0 + gq*32 + l32)*HDD + hf*8];
#pragma unroll
    for (int s = 0; s < 4; s++) qf[s] = *(const short8*)&qp[s*16];
  }
  floatx16 fz16;
#pragma unroll
  for (int z = 0; z < 16; z++) fz16[z] = 0.f;
  floatx16 oacc[2];
  oacc[0] = fz16; oacc[1] = fz16;
  float lrow = 0.f;

  for (int kt = 0; kt < NN/128; kt++) {
    __syncthreads();                        // prior ks/vt reads done
#pragma unroll
    for (int i = 0; i < 4; i++) {           // stage K tile (16KB) + V^T tile (16KB)
      int c = i*256 + t;
      gld16(&kb[kbase + (size_t)kt*8192 + c*8], &ks[c*8]);
      gld16(&vb[kbase + (size_t)(c >> 4)*NN + kt*128 + (c & 15)*8], &vt[c*8]);
    }
    __syncthreads();                        // drains vmcnt

    // S^T per key-subtile, then exp + in-register bf16 pack (no LDS round-trip)
    short8 pfr[4];                          // PV A-frags: k-slices kh*4 .. kh*4+3
    float rs = 0.f;
#pragma unroll
    for (int tt = 0; tt < 2; tt++) {
      int t2 = kh*2 + tt;
      int row = t2*32 + l32;
      floatx16 acc;
#pragma unroll
      for (int z = 0; z < 16; z++) acc[z] = 0.f;
      __builtin_amdgcn_s_setprio(1);
#pragma unroll
      for (int s = 0; s < 4; s++) {
        int cd = (2*s + hf) ^ (l32 & 7);    // un-swizzle d-chunk
        short8 kf = *(const short8*)&ks[row*64 + cd*8];
        acc = __builtin_amdgcn_mfma_f32_32x32x16_bf16(kf, qf[s], acc, 0, 0, 0);
      }
      __builtin_amdgcn_s_setprio(0);
      float pv_[16];
#pragma unroll
      for (int r = 0; r < 16; r++) { pv_[r] = __expf(acc[r]); rs += pv_[r]; }
      // lane holds subtile-keys (r&3)+8*(r>>2)+4*hf. Pack pairs; permlane32_swap
      // exchanges hf halves: swap(cvtpk(p0,p1), cvtpk(p4,p5)) yields frag words
      // 0 and 2 of the low k-slice; p8..p15 likewise for the high k-slice.
      unsigned int w0 = cvtpk_bf16(pv_[0],  pv_[1]);
      unsigned int w1 = cvtpk_bf16(pv_[2],  pv_[3]);
      unsigned int w2 = cvtpk_bf16(pv_[4],  pv_[5]);
      unsigned int w3 = cvtpk_bf16(pv_[6],  pv_[7]);
      unsigned int w4 = cvtpk_bf16(pv_[8],  pv_[9]);
      unsigned int w5 = cvtpk_bf16(pv_[10], pv_[11]);
      unsigned int w6 = cvtpk_bf16(pv_[12], pv_[13]);
      unsigned int w7 = cvtpk_bf16(pv_[14], pv_[15]);
      plswap(w0, w2); plswap(w1, w3);       // -> keys t2*32 + 0..15
      plswap(w4, w6); plswap(w5, w7);       // -> keys t2*32 + 16..31
      uintx4 ua = {w0, w1, w2, w3};
      uintx4 ub = {w4, w5, w6, w7};
      pfr[2*tt+0] = __builtin_bit_cast(short8, ua);
      pfr[2*tt+1] = __builtin_bit_cast(short8, ub);
    }
    rs += __shfl_xor(rs, 32);               // combine hf halves (keys within subtiles)
    lrow += rs;                             // partial l over this wave's key-half
    // O += P.V over this wave's 4 k-slices, P straight from registers
    __builtin_amdgcn_s_setprio(1);
#pragma unroll
    for (int ss = 0; ss < 4; ss++) {
      int s2 = kh*4 + ss;
      int ca = (s2*2 + hf) ^ (l32 & 7);     // un-swizzle key-chunk
      short8 pf = pfr[ss];
#pragma unroll
      for (int ht = 0; ht < 2; ht++) {
        int hd = ht*32 + l32;
        short8 vf = *(const short8*)&vt[hd*128 + ca*8];  // (hd&7)==(l32&7)
        oacc[ht] = __builtin_amdgcn_mfma_f32_32x32x16_bf16(pf, vf, oacc[ht], 0, 0, 0);
      }
    }
    __builtin_amdgcn_s_setprio(0);
  }
  // ---- cross-wave merge: O = O_kh0 + O_kh1, l = l_kh0 + l_kh1 ----
  __syncthreads();                          // all ks/vt reads done; ks reused as fp32
  float* om = (float*)ks;                   // 2 groups x 32q x 64hd floats = 16KB
  if (kh) {
    float* base = om + gq*2048;
#pragma unroll
    for (int ht = 0; ht < 2; ht++)
#pragma unroll
      for (int g = 0; g < 4; g++)
#pragma unroll
        for (int e = 0; e < 4; e++) {
          int ql = hf*4 + g*8 + e;          // C-layout row within q-group
          base[ql*64 + ht*32 + l32] = oacc[ht][4*g+e];
        }
  }
  if (hf == 0) lsd[w*32 + l32] = lrow;      // both hf halves hold the sum; one writes
  __syncthreads();
  if (!kh) {
    float* base = om + gq*2048;
#pragma unroll
    for (int g = 0; g < 4; g++)
#pragma unroll
      for (int e = 0; e < 4; e++) {
        int ql = hf*4 + g*8 + e;
        float l = lsd[gq*64 + ql] + lsd[gq*64 + 32 + ql];
        float inv = 1.f / l;
        int qrow = q0 + gq*32 + ql;
#pragma unroll
        for (int ht = 0; ht < 2; ht++) {
          float v = oacc[ht][4*g+e] + base[ql*64 + ht*32 + l32];
          ob[((size_t)(b*NN + qrow))*DD + hh*HDD + ht*32 + l32] = f2bf(v * inv);
        }
      }
  }
}

extern "C" void kernel_launch(void* const* d_in, const int* in_sizes, int n_in,
                              void* d_out, int out_size, void* d_ws, size_t ws_size,
                              hipStream_t stream)
{
  const float* x     = (const float*)d_in[0];
  const float* pos   = (const float*)d_in[1];
  const float* Wqkv  = (const float*)d_in[2];
  const float* Wproj = (const float*)d_in[3];
  const float* bproj = (const float*)d_in[4];

  unsigned short* p = (unsigned short*)d_ws;
  unsigned short* xb     = p; p += (size_t)MM*DD;
  unsigned short* wqkvb  = p; p += (size_t)3*DD*DD;
  unsigned short* wprojb = p; p += (size_t)DD*DD;
  unsigned short* ob     = p; p += (size_t)MM*DD;       // attn out (b,n,d) bf16
  unsigned short* qb     = p; p += (size_t)BB*HH*NN*HDD;
  unsigned short* kb     = p; p += (size_t)BB*HH*NN*HDD;
  unsigned short* vb     = p; p += (size_t)BB*HH*NN*HDD;

  const int ncvt = MM*DD/4 + 3*DD*DD/4 + DD*DD/4;   // 1376256 = 5376*256
  cvt_all<<<ncvt/256, 256, 0, stream>>>(x, Wqkv, Wproj, xb, wqkvb, wprojb);

  gemm_bt<2,64,128,64><<<dim3(3*DD/128, MM/64), 256, 0, stream>>>(
      xb, wqkvb, nullptr, nullptr, 3*DD, DD, pos, qb, kb, vb);
  flash_attn<<<dim3(NN/64, BB*HH), 256, 0, stream>>>(qb, kb, vb, ob);
  gemm_bt<1,64,64,64><<<dim3(DD/64, MM/64), 256, 0, stream>>>(
      ob, wprojb, (float*)d_out, bproj, DD, DD, nullptr, nullptr, nullptr, nullptr);
}